// Round 1
// 498.850 us; speedup vs baseline: 1.0234x; 1.0234x over previous
//
#include <hip/hip_runtime.h>
#include <math.h>

#define T_DIM 1000
#define C_DIM 500
#define U_DIM 100
#define PAD   16          // head/tail padding rows for P
#define AROWS (T_DIM + 5) // A/Braw rows (loss pipeline reads to row T+4)
#define NEGINF (-INFINITY)

__device__ __forceinline__ float lse2f(float a, float b) {
    float m = fmaxf(a, b);
    if (m == NEGINF) return NEGINF;
    float mn = fminf(a, b);
    return m + __logf(1.0f + __expf(mn - m));
}

__device__ __forceinline__ float lse3f(float x1, float x2, float x3) {
    float m = fmaxf(fmaxf(x1, x2), x3);
    if (m == NEGINF) return NEGINF;
    return m + __logf(__expf(x1 - m) + __expf(x2 - m) + __expf(x3 - m));
}

// Bug-compatible replica of reference _log_sub_exp (incl. inf-substitution quirk).
__device__ __forceinline__ float log_sub_expf(float a, float b) {
    bool ia = isinf(a), ib = isinf(b);
    if (!ia && !ib) {
        float ans = b + __logf(__expf(a - b) - 1.0f);
        if (isinf(ans)) ans = -2001.0f + __logf(__expf(1.0f) - 1.0f);
        return ans;
    }
    if (!ia && ib) return a;
    return NEGINF;
}

// DPP lane shifts (validated bit-exact rounds 6-10)
__device__ __forceinline__ float dpp_shr1(float x) {  // lane L <- L-1; lane0 <- -inf
    int r = __builtin_amdgcn_update_dpp(__float_as_int(NEGINF), __float_as_int(x),
                                        0x138, 0xF, 0xF, false);  // wave_shr:1
    return __int_as_float(r);
}
__device__ __forceinline__ float dpp_shl1(float x) {  // lane L <- L+1; lane63 <- -inf
    int r = __builtin_amdgcn_update_dpp(__float_as_int(NEGINF), __float_as_int(x),
                                        0x130, 0xF, 0xF, false);  // wave_shl:1
    return __int_as_float(r);
}

// ---- scan step macros (bit-identical formulas to r10) ----------------------
#define FWD_STEP(tt, PL, PBV)                                                \
    {                                                                        \
        float p0 = v0 ? (PBV)  : NEGINF;                                     \
        float p1 = v1 ? (PL).x : NEGINF;                                     \
        float p2 = v2 ? (PBV)  : NEGINF;                                     \
        float p3 = v3 ? (PL).y : NEGINF;                                     \
        float am1 = dpp_shr1(a3);                                            \
        float n0 = p0 + lse2f(a0, am1);                                      \
        float n1 = p1 + lse3f(a1, a0, skip1 ? am1 : NEGINF);                 \
        float n2 = p2 + lse2f(a2, a1);                                       \
        float n3 = p3 + lse3f(a3, a2, skip3 ? a1 : NEGINF);                  \
        a0 = n0; a1 = n1; a2 = n2; a3 = n3;                                  \
        if (st) {                                                            \
            bool live = ((tt) < hl);                                         \
            ((float2*)(Ab + (size_t)(tt) * U_DIM))[L] =                      \
                make_float2(live ? n1 : NEGINF, live ? n3 : NEGINF);         \
        }                                                                    \
    }

#define BWD_STEP(tt, PL, PBV)                                                \
    {                                                                        \
        float ph0 = v0 ? (PBV)  : NEGINF;                                    \
        float ph1 = v1 ? (PL).x : NEGINF;                                    \
        float ph2 = v2 ? (PBV)  : NEGINF;                                    \
        float ph3 = v3 ? (PL).y : NEGINF;                                    \
        float q0 = ph0 + b0, q1 = ph1 + b1, q2 = ph2 + b2, q3 = ph3 + b3;    \
        float qd0 = dpp_shl1(q0);                                            \
        float qd1 = dpp_shl1(q1);                                            \
        float n0 = lse2f(q0, q1);                                            \
        float n1 = lse3f(q1, q2, skipA ? q3 : NEGINF);                       \
        float n2 = lse2f(q2, q3);                                            \
        float n3 = lse3f(q3, qd0, skipB ? qd1 : NEGINF);                     \
        bool fin = ((tt) == hl - 1);                                         \
        b0 = fin ? f0 : n0;                                                  \
        b1 = fin ? f1 : n1;                                                  \
        b2 = fin ? f2 : n2;                                                  \
        b3 = fin ? f3 : n3;                                                  \
        if (st)                                                              \
            ((float2*)(Bb + (size_t)(tt) * U_DIM))[L] = make_float2(b1, b3); \
    }

// LDS float2 read: lane L of row rr (row stride 100 floats)
#define LDF(buf, rr) (((const float2*)((buf) + (rr) * 100))[L])

// ---- loss step (verbatim r10) ----------------------------------------------
#define LSTEP(tt, RA, RB, RP)                                                \
    {                                                                        \
        float a_nx = (RA), br_nx = (RB), p_nx = (RP);                        \
        float bl   = (a_t  == NEGINF) ? NEGINF : braw_t;                     \
        float term = (a_nx == NEGINF) ? NEGINF : (br_nx + p_nx);             \
        float bp = log_sub_expf(bl, term);                                   \
        float x = a_t + bp - 0.1f * (float)(tt) * inv_hl;                    \
        if (x != NEGINF) {                                                   \
            float nm = fmaxf(m, x);                                          \
            ssum = ssum * __expf(m - nm) + __expf(x - nm);                   \
            m = nm;                                                          \
        }                                                                    \
        a_t = a_nx; braw_t = br_nx;                                          \
    }

// ---- loader gather: 50 rows x (100 labels + blank) straight from nnet ------
// Values are bit-identical to the old pre-gather kernel's P/PB content:
//   row < T_DIM : nnet[row][ys[q]] (labels) / nnet[row][0] (blank)
//   row == T_DIM: -inf sentinel
// Fwd loaders additionally stream the gathered labels to global P (loss phase).
__device__ __forceinline__ void gather_chunk(
    const float* __restrict__ nb, const int* __restrict__ shY,
    float* __restrict__ lds, float* __restrict__ ldsb,
    float* __restrict__ Pg /* global row0 base, or nullptr */,
    int row0, int j)
{
#pragma unroll
    for (int k = 0; k < 15; ++k) {
        int i = j + k * 448;                 // 448 loader threads per direction
        if (i < 6400) {                      // 50 rows x 128 slots
            int r = i >> 7, q = i & 127;
            if (q <= 100) {
                int row = row0 + r;
                int col = (q < 100) ? shY[q] : 0;
                float v = (row < T_DIM) ? nb[(size_t)row * C_DIM + col] : NEGINF;
                if (q < 100) {
                    lds[r * 100 + q] = v;
                    if (Pg) Pg[(size_t)r * U_DIM + q] = v;
                } else {
                    ldsb[r] = v;
                }
            }
        }
    }
}

// ---- fused: LDS double-buffered chunks; loader waves gather from nnet ------
extern "C" __global__ void __launch_bounds__(1024)
brctc_fused(const float* __restrict__ nnet, const int* __restrict__ ys,
            const int* __restrict__ hlens, const int* __restrict__ ylens,
            float* __restrict__ P,
            float* __restrict__ A, float* __restrict__ Braw,
            float* __restrict__ out)
{
    const int b = blockIdx.x;
    const int tid = threadIdx.x;
    const int w = tid >> 6, L = tid & 63;
    const int hl = hlens[b], yl = ylens[b];
    const size_t TP = T_DIM + 2 * PAD;
    const float* nb = nnet + (size_t)b * T_DIM * C_DIM;
    float* Pw = P + ((size_t)b * TP + PAD) * U_DIM;   // rows 0..T (+tail pad)
    const float* Pb = Pw;                             // loss-phase reads
    const int* ysb = ys + b * U_DIM;
    float* Ab = A    + (size_t)b * AROWS * U_DIM;
    float* Bb = Braw + (size_t)b * AROWS * U_DIM;

    // LDS: 2 dirs x 2 buffers x 50 rows x 100 floats (+ tail pad for lane>=50 reads)
    __shared__ __align__(16) float fbuf[2][5056];
    __shared__ __align__(16) float bbuf[2][5056];
    __shared__ float fpb[2][56], bpb[2][56];
    __shared__ float shm[8][U_DIM], shs[8][U_DIM], shlu[U_DIM];
    __shared__ int shY[U_DIM];

    if (tid < U_DIM) shY[tid] = ysb[tid];

    // ---- per-lane scan constants (computed by all threads, used by waves 0/1)
    const int s0_ = 4 * L, s1 = 4 * L + 1, s2_ = 4 * L + 2, s3 = 4 * L + 3;
    const int u1 = 2 * L;
    const int lab1 = ysb[min(u1, U_DIM - 1)];
    const int lab3 = ysb[min(u1 + 1, U_DIM - 1)];
    const int labm = ysb[min(max(u1 - 1, 0), U_DIM - 1)];
    const int labn = ysb[min(u1 + 2, U_DIM - 1)];
    const bool skip1 = (s1 >= 3) && (lab1 != labm);
    const bool skip3 = (lab3 != lab1);
    const bool skipA = (s1 < 199) && (lab3 != lab1);
    const bool skipB = (s3 < 199) && (labn != lab3);
    const int ty = 2 * yl;
    const bool v0 = (s0_ <= 200) && (s0_ <= ty);
    const bool v1 = (s1  <= 200) && (s1  <= ty);
    const bool v2 = (s2_ <= 200) && (s2_ <= ty);
    const bool v3 = (s3  <= 200) && (s3  <= ty);
    const bool st = (L < 50);
    const float f0 = (s0_ == ty || s0_ == ty - 1) ? 0.0f : NEGINF;
    const float f1 = (s1  == ty || s1  == ty - 1) ? 0.0f : NEGINF;
    const float f2 = (s2_ == ty || s2_ == ty - 1) ? 0.0f : NEGINF;
    const float f3 = (s3  == ty || s3  == ty - 1) ? 0.0f : NEGINF;

    float a0 = (L == 0) ? 0.0f : NEGINF, a1 = NEGINF, a2 = NEGINF, a3 = NEGINF;
    float b0 = NEGINF, b1 = NEGINF, b2 = NEGINF, b3 = NEGINF;

    __syncthreads();   // shY ready for loaders

    // ---- prologue: gather fwd chunk 0 (rows 0..49) and bwd chunk 19 (951..1000)
    if (w >= 2 && w < 9) {                 // fwd loaders (waves 2..8, 448 thr)
        int j = tid - 128;
        gather_chunk(nb, shY, fbuf[0], fpb[0], Pw, 0, j);
        if (j < U_DIM) Pw[(size_t)T_DIM * U_DIM + j] = NEGINF;  // global P row 1000
    } else if (w >= 9) {                   // bwd loaders (waves 9..15)
        int j = tid - 576;
        gather_chunk(nb, shY, bbuf[0], bpb[0], nullptr, 951, j);
    }
    __syncthreads();

    // ---- 20 chunks of 50 steps --------------------------------------------
    for (int c = 0; c < 20; ++c) {
        if (w == 0) {                       // forward scan, chunk c
            const float* fb = fbuf[c & 1];
            const float* fp = fpb[c & 1];
            const int tb = 50 * c;
            for (int kk = 0; kk < 50; kk += 10) {
                float2 r0 = LDF(fb, kk + 0), r1 = LDF(fb, kk + 1);
                float2 r2 = LDF(fb, kk + 2), r3 = LDF(fb, kk + 3);
                float2 r4 = LDF(fb, kk + 4), r5 = LDF(fb, kk + 5);
                float2 r6 = LDF(fb, kk + 6), r7 = LDF(fb, kk + 7);
                float2 r8 = LDF(fb, kk + 8), r9 = LDF(fb, kk + 9);
                float g0 = fp[kk + 0], g1 = fp[kk + 1], g2 = fp[kk + 2];
                float g3 = fp[kk + 3], g4 = fp[kk + 4], g5 = fp[kk + 5];
                float g6 = fp[kk + 6], g7 = fp[kk + 7], g8 = fp[kk + 8];
                float g9 = fp[kk + 9];
                FWD_STEP(tb + kk + 0, r0, g0)
                FWD_STEP(tb + kk + 1, r1, g1)
                FWD_STEP(tb + kk + 2, r2, g2)
                FWD_STEP(tb + kk + 3, r3, g3)
                FWD_STEP(tb + kk + 4, r4, g4)
                FWD_STEP(tb + kk + 5, r5, g5)
                FWD_STEP(tb + kk + 6, r6, g6)
                FWD_STEP(tb + kk + 7, r7, g7)
                FWD_STEP(tb + kk + 8, r8, g8)
                FWD_STEP(tb + kk + 9, r9, g9)
            }
        } else if (w == 1) {                // backward scan, chunk 19-c
            const float* bbf = bbuf[c & 1];
            const float* bp  = bpb[c & 1];
            const int cc = 19 - c;
            const int tb = 50 * cc;         // steps tb+49 .. tb; slot = t - tb
            for (int kk = 49; kk >= 9; kk -= 10) {
                float2 r0 = LDF(bbf, kk - 0), r1 = LDF(bbf, kk - 1);
                float2 r2 = LDF(bbf, kk - 2), r3 = LDF(bbf, kk - 3);
                float2 r4 = LDF(bbf, kk - 4), r5 = LDF(bbf, kk - 5);
                float2 r6 = LDF(bbf, kk - 6), r7 = LDF(bbf, kk - 7);
                float2 r8 = LDF(bbf, kk - 8), r9 = LDF(bbf, kk - 9);
                float g0 = bp[kk - 0], g1 = bp[kk - 1], g2 = bp[kk - 2];
                float g3 = bp[kk - 3], g4 = bp[kk - 4], g5 = bp[kk - 5];
                float g6 = bp[kk - 6], g7 = bp[kk - 7], g8 = bp[kk - 8];
                float g9 = bp[kk - 9];
                BWD_STEP(tb + kk - 0, r0, g0)
                BWD_STEP(tb + kk - 1, r1, g1)
                BWD_STEP(tb + kk - 2, r2, g2)
                BWD_STEP(tb + kk - 3, r3, g3)
                BWD_STEP(tb + kk - 4, r4, g4)
                BWD_STEP(tb + kk - 5, r5, g5)
                BWD_STEP(tb + kk - 6, r6, g6)
                BWD_STEP(tb + kk - 7, r7, g7)
                BWD_STEP(tb + kk - 8, r8, g8)
                BWD_STEP(tb + kk - 9, r9, g9)
            }
        } else if (c < 19) {                // loaders: gather next buffers from nnet
            if (w < 9) {
                int j = tid - 128;
                int row0 = (c + 1) * 50;                       // rows 50..999
                gather_chunk(nb, shY, fbuf[(c + 1) & 1], fpb[(c + 1) & 1],
                             Pw + (size_t)row0 * U_DIM, row0, j);
            } else {
                int j = tid - 576;
                int row0 = (18 - c) * 50 + 1;                  // rows 1..950
                gather_chunk(nb, shY, bbuf[(c + 1) & 1], bpb[(c + 1) & 1],
                             nullptr, row0, j);
            }
        }
        __syncthreads();
    }
    // sentinel row T = -inf (a_next at t = T-1 in loss phase)
    if (w == 0 && st)
        ((float2*)(Ab + (size_t)T_DIM * U_DIM))[L] = make_float2(NEGINF, NEGINF);
    __syncthreads();

    // ---- loss phase (verbatim r10 structure) ------------------------------
    {
        const int u = tid & 127;
        const int c = tid >> 7;               // 0..7
        if (u < U_DIM) {
            const bool valu = (u < yl);
            const float inv_hl = 1.0f / (float)hl;
            const int t0 = 125 * c;
            float a_t    = Ab[(size_t)t0 * U_DIM + u];
            float braw_t = Bb[(size_t)t0 * U_DIM + u];
            float aA0 = Ab[(long)(t0 + 1) * U_DIM + u];
            float aA1 = Ab[(long)(t0 + 2) * U_DIM + u];
            float aA2 = Ab[(long)(t0 + 3) * U_DIM + u];
            float aA3 = Ab[(long)(t0 + 4) * U_DIM + u];
            float bA0 = Bb[(long)(t0 + 1) * U_DIM + u];
            float bA1 = Bb[(long)(t0 + 2) * U_DIM + u];
            float bA2 = Bb[(long)(t0 + 3) * U_DIM + u];
            float bA3 = Bb[(long)(t0 + 4) * U_DIM + u];
            float pA0 = valu ? Pb[(long)(t0 + 1) * U_DIM + u] : NEGINF;
            float pA1 = valu ? Pb[(long)(t0 + 2) * U_DIM + u] : NEGINF;
            float pA2 = valu ? Pb[(long)(t0 + 3) * U_DIM + u] : NEGINF;
            float pA3 = valu ? Pb[(long)(t0 + 4) * U_DIM + u] : NEGINF;
            float m = NEGINF, ssum = 0.0f;
            for (int kb = 0; kb <= 120; kb += 4) {
                long nr = (long)(t0 + kb + 5);
                float aB0 = Ab[(nr + 0) * U_DIM + u];
                float aB1 = Ab[(nr + 1) * U_DIM + u];
                float aB2 = Ab[(nr + 2) * U_DIM + u];
                float aB3 = Ab[(nr + 3) * U_DIM + u];
                float bB0 = Bb[(nr + 0) * U_DIM + u];
                float bB1 = Bb[(nr + 1) * U_DIM + u];
                float bB2 = Bb[(nr + 2) * U_DIM + u];
                float bB3 = Bb[(nr + 3) * U_DIM + u];
                float pB0 = valu ? Pb[(nr + 0) * U_DIM + u] : NEGINF;
                float pB1 = valu ? Pb[(nr + 1) * U_DIM + u] : NEGINF;
                float pB2 = valu ? Pb[(nr + 2) * U_DIM + u] : NEGINF;
                float pB3 = valu ? Pb[(nr + 3) * U_DIM + u] : NEGINF;
                LSTEP(t0 + kb + 0, aA0, bA0, pA0)
                LSTEP(t0 + kb + 1, aA1, bA1, pA1)
                LSTEP(t0 + kb + 2, aA2, bA2, pA2)
                LSTEP(t0 + kb + 3, aA3, bA3, pA3)
                aA0 = aB0; aA1 = aB1; aA2 = aB2; aA3 = aB3;
                bA0 = bB0; bA1 = bB1; bA2 = bB2; bA3 = bB3;
                pA0 = pB0; pA1 = pB1; pA2 = pB2; pA3 = pB3;
            }
            LSTEP(t0 + 124, aA0, bA0, pA0)
            shm[c][u] = m; shs[c][u] = ssum;
        }
    }
    __syncthreads();
    if (tid < U_DIM) {
        float M = NEGINF;
#pragma unroll
        for (int c = 0; c < 8; ++c) M = fmaxf(M, shm[c][tid]);
        float lu = NEGINF;
        if (M != NEGINF) {
            float s = 0.0f;
#pragma unroll
            for (int c = 0; c < 8; ++c) {
                float mc = shm[c][tid];
                if (mc != NEGINF) s += shs[c][tid] * __expf(mc - M);
            }
            lu = M + __logf(s);
        }
        shlu[tid] = lu;
    }
    __syncthreads();
    if (tid == 0) {
        int cnt = 0;
        for (int u = 0; u < U_DIM; ++u) cnt += (shlu[u] != NEGINF) ? 1 : 0;
        int last = cnt - 1;
        last = last < 0 ? 0 : (last > U_DIM - 1 ? U_DIM - 1 : last);
        out[b] = -shlu[last];
    }
}

// =================== fallback (small ws): round-1-style direct path =========
extern "C" __global__ void __launch_bounds__(256)
brctc_fwd_fb(const float* __restrict__ nnet, const int* __restrict__ ys,
             const int* __restrict__ hlens, const int* __restrict__ ylens,
             float* __restrict__ a_l)
{
    const int b = blockIdx.x;
    const int s = threadIdx.x;
    __shared__ float sh_a[201];
    __shared__ int   sh_ys[U_DIM];
    if (s < U_DIM) sh_ys[s] = ys[b * U_DIM + s];
    __syncthreads();
    const int hl = hlens[b], yl = ylens[b];
    int lab = 0; bool skip = false;
    if (s < 201) {
        if (s & 1) lab = sh_ys[(s - 1) >> 1];
        if ((s & 1) && s >= 3) skip = (sh_ys[(s - 1) >> 1] != sh_ys[(s - 3) >> 1]);
        sh_a[s] = (s == 0) ? 0.0f : NEGINF;
    }
    const bool valid = (s < 201) && (s <= 2 * yl);
    const bool isodd = (s < 201) && (s & 1);
    const int l = (s - 1) >> 1;
    const float* base = nnet + (size_t)b * T_DIM * C_DIM;
    float* alb = a_l + (size_t)b * T_DIM * U_DIM;
    __syncthreads();
    float p_cur = valid ? base[lab] : NEGINF;
    for (int t = 0; t < T_DIM; ++t) {
        float p_nxt = (valid && (t + 1 < T_DIM)) ? base[(size_t)(t + 1) * C_DIM + lab] : NEGINF;
        float x1 = (s < 201) ? sh_a[s] : NEGINF;
        float x2 = (s >= 1 && s < 201) ? sh_a[s - 1] : NEGINF;
        float x3 = skip ? sh_a[s - 2] : NEGINF;
        float anew = p_cur + lse3f(x1, x2, x3);
        __syncthreads();
        if (s < 201) sh_a[s] = anew;
        if (isodd) alb[t * U_DIM + l] = (t < hl) ? anew : NEGINF;
        __syncthreads();
        p_cur = p_nxt;
    }
}

extern "C" __global__ void __launch_bounds__(256)
brctc_bwd_fb(const float* __restrict__ nnet, const int* __restrict__ ys,
             const int* __restrict__ hlens, const int* __restrict__ ylens,
             const float* __restrict__ a_l, float* __restrict__ out)
{
    const int b = blockIdx.x;
    const int s = threadIdx.x;
    __shared__ float sh_b[201], sh_q[201], sh_lu[U_DIM];
    __shared__ int sh_ys[U_DIM];
    if (s < U_DIM) sh_ys[s] = ys[b * U_DIM + s];
    __syncthreads();
    const int hl = hlens[b], yl = ylens[b];
    int lab = 0; bool skip2 = false;
    if (s < 201) {
        if (s & 1) lab = sh_ys[(s - 1) >> 1];
        int s2 = s + 2;
        if (s2 < 201 && (s2 & 1) && s2 >= 3)
            skip2 = (sh_ys[(s2 - 1) >> 1] != sh_ys[(s2 - 3) >> 1]);
        sh_b[s] = NEGINF;
    }
    const bool valid = (s < 201) && (s <= 2 * yl);
    const bool isodd = (s < 201) && (s & 1);
    const int l = (s - 1) >> 1;
    const float fin0 = (s == 2 * yl || s == 2 * yl - 1) ? 0.0f : NEGINF;
    const float* base = nnet + (size_t)b * T_DIM * C_DIM;
    const float* alb = a_l + (size_t)b * T_DIM * U_DIM;
    float m_run = NEGINF, acc = 0.0f, prev_bl = NEGINF, p_hi = NEGINF;
    __syncthreads();
    for (int t = T_DIM - 1; t >= 0; --t) {
        float p_lo = valid ? base[(size_t)t * C_DIM + lab] : NEGINF;
        float a_cur = isodd ? alb[t * U_DIM + l] : NEGINF;
        float q = (s < 201) ? (p_hi + sh_b[s]) : NEGINF;
        if (s < 201) sh_q[s] = q;
        __syncthreads();
        float q2 = (s + 1 < 201) ? sh_q[s + 1] : NEGINF;
        float q3 = skip2 ? sh_q[s + 2] : NEGINF;
        float cand = lse3f(q, q2, q3);
        float bnew = (t == hl - 1) ? fin0 : cand;
        if (s < 201) sh_b[s] = bnew;
        if (isodd) {
            float bl_t = (a_cur == NEGINF) ? NEGINF : bnew;
            float bp = (t == T_DIM - 1) ? bl_t : log_sub_expf(bl_t, prev_bl + p_hi);
            float x = a_cur + bp - 0.1f * ((float)t / (float)hl);
            if (x != NEGINF) {
                if (x <= m_run) acc += __expf(x - m_run);
                else { acc = acc * __expf(m_run - x) + 1.0f; m_run = x; }
            }
            prev_bl = bl_t;
        }
        __syncthreads();
        p_hi = p_lo;
    }
    if (isodd) sh_lu[l] = (m_run == NEGINF) ? NEGINF : (m_run + __logf(acc));
    __syncthreads();
    if (s == 0) {
        int cnt = 0;
        for (int u = 0; u < U_DIM; ++u) cnt += (sh_lu[u] != NEGINF) ? 1 : 0;
        int last = cnt - 1;
        last = last < 0 ? 0 : (last > U_DIM - 1 ? U_DIM - 1 : last);
        out[b] = -sh_lu[last];
    }
}

extern "C" void kernel_launch(void* const* d_in, const int* in_sizes, int n_in,
                              void* d_out, int out_size, void* d_ws, size_t ws_size,
                              hipStream_t stream) {
    const float* nnet  = (const float*)d_in[0];
    const int*   ys    = (const int*)d_in[1];
    const int*   hlens = (const int*)d_in[2];
    const int*   ylens = (const int*)d_in[3];
    float*       outp  = (float*)d_out;
    const int B = in_sizes[2];
    const size_t TP = T_DIM + 2 * PAD;
    const size_t szP  = (size_t)B * TP * U_DIM;
    const size_t szA  = (size_t)B * AROWS * U_DIM;
    const size_t need = (szP + 2 * szA) * sizeof(float);

    if (ws_size >= need) {
        float* P    = (float*)d_ws;
        float* A    = P + szP;
        float* Braw = A + szA;
        brctc_fused<<<B, 1024, 0, stream>>>(nnet, ys, hlens, ylens, P, A, Braw, outp);
    } else {
        float* A = (float*)d_ws;
        brctc_fwd_fb<<<B, 256, 0, stream>>>(nnet, ys, hlens, ylens, A);
        brctc_bwd_fb<<<B, 256, 0, stream>>>(nnet, ys, hlens, ylens, A, outp);
    }
}

// Round 2
// 431.785 us; speedup vs baseline: 1.1824x; 1.1553x over previous
//
#include <hip/hip_runtime.h>
#include <math.h>

#define T_DIM 1000
#define C_DIM 500
#define U_DIM 100
#define PAD   16          // head/tail padding rows for P
#define AROWS (T_DIM + 5) // A/Braw rows (loss pipeline reads to row T+4)
#define NEGINF (-INFINITY)
#define LROW  128         // LDS row stride in floats; cols 100..127 = -inf pad

typedef float v2f __attribute__((ext_vector_type(2)));

__device__ __forceinline__ v2f splat2(float x) { v2f r; r[0] = x; r[1] = x; return r; }

// ---- packed (2-wide) lse helpers: per-component bit-identical to the scalar
// lse2f/lse3f used in rounds 6-11 (same op order; NEGINF handled by select).
__device__ __forceinline__ v2f lse2p(v2f X, v2f Y) {
    v2f m, mn;
    m[0]  = fmaxf(X[0], Y[0]); m[1]  = fmaxf(X[1], Y[1]);
    mn[0] = fminf(X[0], Y[0]); mn[1] = fminf(X[1], Y[1]);
    v2f d = mn - m;                       // packed
    v2f e; e[0] = __expf(d[0]); e[1] = __expf(d[1]);
    v2f s = splat2(1.0f) + e;             // packed (1.0f + e, as reference)
    v2f l; l[0] = __logf(s[0]); l[1] = __logf(s[1]);
    v2f r = m + l;                        // packed
    r[0] = (m[0] == NEGINF) ? NEGINF : r[0];
    r[1] = (m[1] == NEGINF) ? NEGINF : r[1];
    return r;
}

__device__ __forceinline__ v2f lse3p(v2f x1, v2f x2, v2f x3) {
    v2f m;
    m[0] = fmaxf(fmaxf(x1[0], x2[0]), x3[0]);
    m[1] = fmaxf(fmaxf(x1[1], x2[1]), x3[1]);
    v2f d1 = x1 - m, d2 = x2 - m, d3 = x3 - m;    // packed
    v2f e1, e2, e3;
    e1[0] = __expf(d1[0]); e1[1] = __expf(d1[1]);
    e2[0] = __expf(d2[0]); e2[1] = __expf(d2[1]);
    e3[0] = __expf(d3[0]); e3[1] = __expf(d3[1]);
    v2f s = (e1 + e2) + e3;               // packed, same assoc as reference
    v2f l; l[0] = __logf(s[0]); l[1] = __logf(s[1]);
    v2f r = m + l;                        // packed
    r[0] = (m[0] == NEGINF) ? NEGINF : r[0];
    r[1] = (m[1] == NEGINF) ? NEGINF : r[1];
    return r;
}

// scalar lse3 for the fallback kernels
__device__ __forceinline__ float lse3f(float x1, float x2, float x3) {
    float m = fmaxf(fmaxf(x1, x2), x3);
    if (m == NEGINF) return NEGINF;
    return m + __logf(__expf(x1 - m) + __expf(x2 - m) + __expf(x3 - m));
}

// Bug-compatible replica of reference _log_sub_exp (incl. inf-substitution quirk).
__device__ __forceinline__ float log_sub_expf(float a, float b) {
    bool ia = isinf(a), ib = isinf(b);
    if (!ia && !ib) {
        float ans = b + __logf(__expf(a - b) - 1.0f);
        if (isinf(ans)) ans = -2001.0f + __logf(__expf(1.0f) - 1.0f);
        return ans;
    }
    if (!ia && ib) return a;
    return NEGINF;
}

// DPP lane shifts (validated bit-exact rounds 6-10)
__device__ __forceinline__ float dpp_shr1(float x) {  // lane L <- L-1; lane0 <- -inf
    int r = __builtin_amdgcn_update_dpp(__float_as_int(NEGINF), __float_as_int(x),
                                        0x138, 0xF, 0xF, false);  // wave_shr:1
    return __int_as_float(r);
}
__device__ __forceinline__ float dpp_shl1(float x) {  // lane L <- L+1; lane63 <- -inf
    int r = __builtin_amdgcn_update_dpp(__float_as_int(NEGINF), __float_as_int(x),
                                        0x130, 0xF, 0xF, false);  // wave_shl:1
    return __int_as_float(r);
}

// ---- packed scan step macros (values bit-identical to r10 formulas) --------
// State: A02=(a0,a2), A13=(a1,a3).  P13 comes pre-masked from LDS (labels
// with u>=yl and pad lanes are NEGINF there); blank mask mz02 in {0,-inf}.
#define FWD_STEP(tt, PL, PBV)                                                \
    {                                                                        \
        v2f P02 = mz02 + splat2(PBV);                                        \
        float am1 = dpp_shr1(A13[1]);                                        \
        v2f Y;  Y[0] = am1;  Y[1] = A13[0];                                  \
        v2f x3; x3[0] = skip1 ? am1 : NEGINF;                                \
        x3[1] = skip3 ? A13[0] : NEGINF;                                     \
        v2f n02 = P02 + lse2p(A02, Y);                                       \
        v2f n13 = (PL) + lse3p(A13, A02, x3);                                \
        A02 = n02; A13 = n13;                                                \
        if (st)                                                              \
            ((float2*)(Ab + (size_t)(tt) * U_DIM))[L] =                      \
                make_float2(n13[0], n13[1]);                                 \
    }

#define BWD_STEP(tt, PL, PBV)                                                \
    {                                                                        \
        v2f Q02 = (mz02 + splat2(PBV)) + B02;                                \
        v2f Q13 = (PL) + B13;                                                \
        float qd0 = dpp_shl1(Q02[0]);                                        \
        float qd1 = dpp_shl1(Q13[0]);                                        \
        v2f x2; x2[0] = Q02[1]; x2[1] = qd0;                                 \
        v2f x3; x3[0] = skipA ? Q13[1] : NEGINF;                             \
        x3[1] = skipB ? qd1 : NEGINF;                                        \
        v2f n02 = lse2p(Q02, Q13);                                           \
        v2f n13 = lse3p(Q13, x2, x3);                                        \
        bool fin = ((tt) == hl - 1);                                         \
        B02[0] = fin ? f0 : n02[0]; B02[1] = fin ? f2 : n02[1];              \
        B13[0] = fin ? f1 : n13[0]; B13[1] = fin ? f3 : n13[1];              \
        if (st)                                                              \
            ((float2*)(Bb + (size_t)(tt) * U_DIM))[L] =                      \
                make_float2(B13[0], B13[1]);                                 \
    }

// LDS float2 read: lane L of row rr (row stride LROW floats, -inf pads)
#define LDF(buf, rr) (((const v2f*)((buf) + (rr) * LROW))[L])

// ---- loss step (verbatim r10) ----------------------------------------------
#define LSTEP(tt, RA, RB, RP)                                                \
    {                                                                        \
        float a_nx = (RA), br_nx = (RB), p_nx = (RP);                        \
        float bl   = (a_t  == NEGINF) ? NEGINF : braw_t;                     \
        float term = (a_nx == NEGINF) ? NEGINF : (br_nx + p_nx);             \
        float bp = log_sub_expf(bl, term);                                   \
        float x = a_t + bp - 0.1f * (float)(tt) * inv_hl;                    \
        if (x != NEGINF) {                                                   \
            float nm = fmaxf(m, x);                                          \
            ssum = ssum * __expf(m - nm) + __expf(x - nm);                   \
            m = nm;                                                          \
        }                                                                    \
        a_t = a_nx; braw_t = br_nx;                                          \
    }

// ---- loader gather: 50 rows x (100 labels + blank) straight from nnet ------
// LDS copy is pre-masked: labels with u >= yl -> NEGINF (same as the old
// per-step v1/v3 cndmask); global P keeps raw values (loss masks itself).
__device__ __forceinline__ void gather_chunk(
    const float* __restrict__ nb, const int* __restrict__ shY, int yl,
    float* __restrict__ lds, float* __restrict__ ldsb,
    float* __restrict__ Pg /* global row0 base, or nullptr */,
    int row0, int j)
{
#pragma unroll
    for (int k = 0; k < 15; ++k) {
        int i = j + k * 448;                 // 448 loader threads per direction
        if (i < 6400) {                      // 50 rows x 128 slots
            int r = i >> 7, q = i & 127;
            if (q <= 100) {
                int row = row0 + r;
                int col = (q < 100) ? shY[q] : 0;
                float v = (row < T_DIM) ? nb[(size_t)row * C_DIM + col] : NEGINF;
                if (q < 100) {
                    lds[r * LROW + q] = (q < yl) ? v : NEGINF;
                    if (Pg) Pg[(size_t)r * U_DIM + q] = v;
                } else {
                    ldsb[r] = v;
                }
            }
        }
    }
}

// ---- fused: LDS double-buffered chunks; loader waves gather from nnet ------
extern "C" __global__ void __launch_bounds__(1024)
brctc_fused(const float* __restrict__ nnet, const int* __restrict__ ys,
            const int* __restrict__ hlens, const int* __restrict__ ylens,
            float* __restrict__ P,
            float* __restrict__ A, float* __restrict__ Braw,
            float* __restrict__ out)
{
    const int b = blockIdx.x;
    const int tid = threadIdx.x;
    const int w = tid >> 6, L = tid & 63;
    const int hl = hlens[b], yl = ylens[b];
    const size_t TP = T_DIM + 2 * PAD;
    const float* nb = nnet + (size_t)b * T_DIM * C_DIM;
    float* Pw = P + ((size_t)b * TP + PAD) * U_DIM;   // rows 0..T (+tail pad)
    const float* Pb = Pw;                             // loss-phase reads
    const int* ysb = ys + b * U_DIM;
    float* Ab = A    + (size_t)b * AROWS * U_DIM;
    float* Bb = Braw + (size_t)b * AROWS * U_DIM;

    // LDS: 2 dirs x 2 buffers x 50 rows x LROW floats (cols>=100 are -inf pad)
    __shared__ __align__(16) float fbuf[2][50 * LROW];
    __shared__ __align__(16) float bbuf[2][50 * LROW];
    __shared__ float fpb[2][56], bpb[2][56];
    __shared__ float shm[8][U_DIM], shs[8][U_DIM], shlu[U_DIM];
    __shared__ int shY[U_DIM];

    if (tid < U_DIM) shY[tid] = ysb[tid];

    // ---- per-lane scan constants (computed by all threads, used by waves 0/1)
    const int s0_ = 4 * L, s1 = 4 * L + 1, s2_ = 4 * L + 2, s3 = 4 * L + 3;
    const int u1 = 2 * L;
    const int lab1 = ysb[min(u1, U_DIM - 1)];
    const int lab3 = ysb[min(u1 + 1, U_DIM - 1)];
    const int labm = ysb[min(max(u1 - 1, 0), U_DIM - 1)];
    const int labn = ysb[min(u1 + 2, U_DIM - 1)];
    const bool skip1 = (s1 >= 3) && (lab1 != labm);
    const bool skip3 = (lab3 != lab1);
    const bool skipA = (s1 < 199) && (lab3 != lab1);
    const bool skipB = (s3 < 199) && (labn != lab3);
    const int ty = 2 * yl;
    const bool v0 = (s0_ <= 200) && (s0_ <= ty);
    const bool v2_ = (s2_ <= 200) && (s2_ <= ty);
    const bool st = (L < 50);
    v2f mz02; mz02[0] = v0 ? 0.0f : NEGINF; mz02[1] = v2_ ? 0.0f : NEGINF;
    const float f0 = (s0_ == ty || s0_ == ty - 1) ? 0.0f : NEGINF;
    const float f1 = (s1  == ty || s1  == ty - 1) ? 0.0f : NEGINF;
    const float f2 = (s2_ == ty || s2_ == ty - 1) ? 0.0f : NEGINF;
    const float f3 = (s3  == ty || s3  == ty - 1) ? 0.0f : NEGINF;

    v2f A02, A13, B02, B13;
    A02[0] = (L == 0) ? 0.0f : NEGINF; A02[1] = NEGINF;
    A13[0] = NEGINF; A13[1] = NEGINF;
    B02[0] = NEGINF; B02[1] = NEGINF;
    B13[0] = NEGINF; B13[1] = NEGINF;

    __syncthreads();   // shY ready for loaders

    // ---- prologue: -inf pads (once) + gather fwd chunk 0, bwd chunk 19 ----
    if (w >= 2) {
        int j2 = tid - 128;                 // 0..895
        for (int i = j2; i < 4 * 50 * 28; i += 896) {
            int buf = i / (50 * 28), rem = i % (50 * 28);
            int r = rem / 28, q = 100 + rem % 28;
            float* base = (buf == 0) ? fbuf[0] : (buf == 1) ? fbuf[1]
                        : (buf == 2) ? bbuf[0] : bbuf[1];
            base[r * LROW + q] = NEGINF;
        }
    }
    if (w >= 2 && w < 9) {                 // fwd loaders (waves 2..8, 448 thr)
        int j = tid - 128;
        gather_chunk(nb, shY, yl, fbuf[0], fpb[0], Pw, 0, j);
        if (j < U_DIM) Pw[(size_t)T_DIM * U_DIM + j] = NEGINF;  // global P row 1000
    } else if (w >= 9) {                   // bwd loaders (waves 9..15)
        int j = tid - 576;
        gather_chunk(nb, shY, yl, bbuf[0], bpb[0], nullptr, 951, j);
    }
    __syncthreads();

    // ---- 20 chunks of 50 steps --------------------------------------------
    for (int c = 0; c < 20; ++c) {
        if (w == 0) {                       // forward scan, chunk c
            const float* fb = fbuf[c & 1];
            const float* fp = fpb[c & 1];
            const int tb = 50 * c;
            for (int kk = 0; kk < 50; kk += 10) {
                v2f r0 = LDF(fb, kk + 0), r1 = LDF(fb, kk + 1);
                v2f r2 = LDF(fb, kk + 2), r3 = LDF(fb, kk + 3);
                v2f r4 = LDF(fb, kk + 4), r5 = LDF(fb, kk + 5);
                v2f r6 = LDF(fb, kk + 6), r7 = LDF(fb, kk + 7);
                v2f r8 = LDF(fb, kk + 8), r9 = LDF(fb, kk + 9);
                float g0 = fp[kk + 0], g1 = fp[kk + 1], g2 = fp[kk + 2];
                float g3 = fp[kk + 3], g4 = fp[kk + 4], g5 = fp[kk + 5];
                float g6 = fp[kk + 6], g7 = fp[kk + 7], g8 = fp[kk + 8];
                float g9 = fp[kk + 9];
                FWD_STEP(tb + kk + 0, r0, g0)
                FWD_STEP(tb + kk + 1, r1, g1)
                FWD_STEP(tb + kk + 2, r2, g2)
                FWD_STEP(tb + kk + 3, r3, g3)
                FWD_STEP(tb + kk + 4, r4, g4)
                FWD_STEP(tb + kk + 5, r5, g5)
                FWD_STEP(tb + kk + 6, r6, g6)
                FWD_STEP(tb + kk + 7, r7, g7)
                FWD_STEP(tb + kk + 8, r8, g8)
                FWD_STEP(tb + kk + 9, r9, g9)
            }
        } else if (w == 1) {                // backward scan, chunk 19-c
            const float* bbf = bbuf[c & 1];
            const float* bp  = bpb[c & 1];
            const int cc = 19 - c;
            const int tb = 50 * cc;         // steps tb+49 .. tb; slot = t - tb
            for (int kk = 49; kk >= 9; kk -= 10) {
                v2f r0 = LDF(bbf, kk - 0), r1 = LDF(bbf, kk - 1);
                v2f r2 = LDF(bbf, kk - 2), r3 = LDF(bbf, kk - 3);
                v2f r4 = LDF(bbf, kk - 4), r5 = LDF(bbf, kk - 5);
                v2f r6 = LDF(bbf, kk - 6), r7 = LDF(bbf, kk - 7);
                v2f r8 = LDF(bbf, kk - 8), r9 = LDF(bbf, kk - 9);
                float g0 = bp[kk - 0], g1 = bp[kk - 1], g2 = bp[kk - 2];
                float g3 = bp[kk - 3], g4 = bp[kk - 4], g5 = bp[kk - 5];
                float g6 = bp[kk - 6], g7 = bp[kk - 7], g8 = bp[kk - 8];
                float g9 = bp[kk - 9];
                BWD_STEP(tb + kk - 0, r0, g0)
                BWD_STEP(tb + kk - 1, r1, g1)
                BWD_STEP(tb + kk - 2, r2, g2)
                BWD_STEP(tb + kk - 3, r3, g3)
                BWD_STEP(tb + kk - 4, r4, g4)
                BWD_STEP(tb + kk - 5, r5, g5)
                BWD_STEP(tb + kk - 6, r6, g6)
                BWD_STEP(tb + kk - 7, r7, g7)
                BWD_STEP(tb + kk - 8, r8, g8)
                BWD_STEP(tb + kk - 9, r9, g9)
            }
        } else if (c < 19) {                // loaders: gather next buffers from nnet
            if (w < 9) {
                int j = tid - 128;
                int row0 = (c + 1) * 50;                       // rows 50..950
                gather_chunk(nb, shY, yl, fbuf[(c + 1) & 1], fpb[(c + 1) & 1],
                             Pw + (size_t)row0 * U_DIM, row0, j);
            } else {
                int j = tid - 576;
                int row0 = (18 - c) * 50 + 1;                  // rows 1..901
                gather_chunk(nb, shY, yl, bbuf[(c + 1) & 1], bpb[(c + 1) & 1],
                             nullptr, row0, j);
            }
        }
        __syncthreads();
    }

    // ---- post-fill: alpha rows >= hl and sentinel row T are NEGINF --------
    // (replaces the per-step `live` masking; matches reference's post-hoc
    //  alpha = where(t < hl, alpha, NEGINF) plus the row-T sentinel)
    {
        const int r0f = min(hl, T_DIM);
        const int nrow = T_DIM + 1 - r0f;
        const int tot = nrow * 50;
        for (int i = tid; i < tot; i += 1024) {
            const int rr = r0f + i / 50, cc2 = i % 50;
            ((float2*)(Ab + (size_t)rr * U_DIM))[cc2] = make_float2(NEGINF, NEGINF);
        }
    }
    __syncthreads();

    // ---- loss phase (verbatim r10 structure) ------------------------------
    {
        const int u = tid & 127;
        const int c = tid >> 7;               // 0..7
        if (u < U_DIM) {
            const bool valu = (u < yl);
            const float inv_hl = 1.0f / (float)hl;
            const int t0 = 125 * c;
            float a_t    = Ab[(size_t)t0 * U_DIM + u];
            float braw_t = Bb[(size_t)t0 * U_DIM + u];
            float aA0 = Ab[(long)(t0 + 1) * U_DIM + u];
            float aA1 = Ab[(long)(t0 + 2) * U_DIM + u];
            float aA2 = Ab[(long)(t0 + 3) * U_DIM + u];
            float aA3 = Ab[(long)(t0 + 4) * U_DIM + u];
            float bA0 = Bb[(long)(t0 + 1) * U_DIM + u];
            float bA1 = Bb[(long)(t0 + 2) * U_DIM + u];
            float bA2 = Bb[(long)(t0 + 3) * U_DIM + u];
            float bA3 = Bb[(long)(t0 + 4) * U_DIM + u];
            float pA0 = valu ? Pb[(long)(t0 + 1) * U_DIM + u] : NEGINF;
            float pA1 = valu ? Pb[(long)(t0 + 2) * U_DIM + u] : NEGINF;
            float pA2 = valu ? Pb[(long)(t0 + 3) * U_DIM + u] : NEGINF;
            float pA3 = valu ? Pb[(long)(t0 + 4) * U_DIM + u] : NEGINF;
            float m = NEGINF, ssum = 0.0f;
            for (int kb = 0; kb <= 120; kb += 4) {
                long nr = (long)(t0 + kb + 5);
                float aB0 = Ab[(nr + 0) * U_DIM + u];
                float aB1 = Ab[(nr + 1) * U_DIM + u];
                float aB2 = Ab[(nr + 2) * U_DIM + u];
                float aB3 = Ab[(nr + 3) * U_DIM + u];
                float bB0 = Bb[(nr + 0) * U_DIM + u];
                float bB1 = Bb[(nr + 1) * U_DIM + u];
                float bB2 = Bb[(nr + 2) * U_DIM + u];
                float bB3 = Bb[(nr + 3) * U_DIM + u];
                float pB0 = valu ? Pb[(nr + 0) * U_DIM + u] : NEGINF;
                float pB1 = valu ? Pb[(nr + 1) * U_DIM + u] : NEGINF;
                float pB2 = valu ? Pb[(nr + 2) * U_DIM + u] : NEGINF;
                float pB3 = valu ? Pb[(nr + 3) * U_DIM + u] : NEGINF;
                LSTEP(t0 + kb + 0, aA0, bA0, pA0)
                LSTEP(t0 + kb + 1, aA1, bA1, pA1)
                LSTEP(t0 + kb + 2, aA2, bA2, pA2)
                LSTEP(t0 + kb + 3, aA3, bA3, pA3)
                aA0 = aB0; aA1 = aB1; aA2 = aB2; aA3 = aB3;
                bA0 = bB0; bA1 = bB1; bA2 = bB2; bA3 = bB3;
                pA0 = pB0; pA1 = pB1; pA2 = pB2; pA3 = pB3;
            }
            LSTEP(t0 + 124, aA0, bA0, pA0)
            shm[c][u] = m; shs[c][u] = ssum;
        }
    }
    __syncthreads();
    if (tid < U_DIM) {
        float M = NEGINF;
#pragma unroll
        for (int c = 0; c < 8; ++c) M = fmaxf(M, shm[c][tid]);
        float lu = NEGINF;
        if (M != NEGINF) {
            float s = 0.0f;
#pragma unroll
            for (int c = 0; c < 8; ++c) {
                float mc = shm[c][tid];
                if (mc != NEGINF) s += shs[c][tid] * __expf(mc - M);
            }
            lu = M + __logf(s);
        }
        shlu[tid] = lu;
    }
    __syncthreads();
    if (tid == 0) {
        int cnt = 0;
        for (int u = 0; u < U_DIM; ++u) cnt += (shlu[u] != NEGINF) ? 1 : 0;
        int last = cnt - 1;
        last = last < 0 ? 0 : (last > U_DIM - 1 ? U_DIM - 1 : last);
        out[b] = -shlu[last];
    }
}

// =================== fallback (small ws): round-1-style direct path =========
extern "C" __global__ void __launch_bounds__(256)
brctc_fwd_fb(const float* __restrict__ nnet, const int* __restrict__ ys,
             const int* __restrict__ hlens, const int* __restrict__ ylens,
             float* __restrict__ a_l)
{
    const int b = blockIdx.x;
    const int s = threadIdx.x;
    __shared__ float sh_a[201];
    __shared__ int   sh_ys[U_DIM];
    if (s < U_DIM) sh_ys[s] = ys[b * U_DIM + s];
    __syncthreads();
    const int hl = hlens[b], yl = ylens[b];
    int lab = 0; bool skip = false;
    if (s < 201) {
        if (s & 1) lab = sh_ys[(s - 1) >> 1];
        if ((s & 1) && s >= 3) skip = (sh_ys[(s - 1) >> 1] != sh_ys[(s - 3) >> 1]);
        sh_a[s] = (s == 0) ? 0.0f : NEGINF;
    }
    const bool valid = (s < 201) && (s <= 2 * yl);
    const bool isodd = (s < 201) && (s & 1);
    const int l = (s - 1) >> 1;
    const float* base = nnet + (size_t)b * T_DIM * C_DIM;
    float* alb = a_l + (size_t)b * T_DIM * U_DIM;
    __syncthreads();
    float p_cur = valid ? base[lab] : NEGINF;
    for (int t = 0; t < T_DIM; ++t) {
        float p_nxt = (valid && (t + 1 < T_DIM)) ? base[(size_t)(t + 1) * C_DIM + lab] : NEGINF;
        float x1 = (s < 201) ? sh_a[s] : NEGINF;
        float x2 = (s >= 1 && s < 201) ? sh_a[s - 1] : NEGINF;
        float x3 = skip ? sh_a[s - 2] : NEGINF;
        float anew = p_cur + lse3f(x1, x2, x3);
        __syncthreads();
        if (s < 201) sh_a[s] = anew;
        if (isodd) alb[t * U_DIM + l] = (t < hl) ? anew : NEGINF;
        __syncthreads();
        p_cur = p_nxt;
    }
}

extern "C" __global__ void __launch_bounds__(256)
brctc_bwd_fb(const float* __restrict__ nnet, const int* __restrict__ ys,
             const int* __restrict__ hlens, const int* __restrict__ ylens,
             const float* __restrict__ a_l, float* __restrict__ out)
{
    const int b = blockIdx.x;
    const int s = threadIdx.x;
    __shared__ float sh_b[201], sh_q[201], sh_lu[U_DIM];
    __shared__ int sh_ys[U_DIM];
    if (s < U_DIM) sh_ys[s] = ys[b * U_DIM + s];
    __syncthreads();
    const int hl = hlens[b], yl = ylens[b];
    int lab = 0; bool skip2 = false;
    if (s < 201) {
        if (s & 1) lab = sh_ys[(s - 1) >> 1];
        int s2 = s + 2;
        if (s2 < 201 && (s2 & 1) && s2 >= 3)
            skip2 = (sh_ys[(s2 - 1) >> 1] != sh_ys[(s2 - 3) >> 1]);
        sh_b[s] = NEGINF;
    }
    const bool valid = (s < 201) && (s <= 2 * yl);
    const bool isodd = (s < 201) && (s & 1);
    const int l = (s - 1) >> 1;
    const float fin0 = (s == 2 * yl || s == 2 * yl - 1) ? 0.0f : NEGINF;
    const float* base = nnet + (size_t)b * T_DIM * C_DIM;
    const float* alb = a_l + (size_t)b * T_DIM * U_DIM;
    float m_run = NEGINF, acc = 0.0f, prev_bl = NEGINF, p_hi = NEGINF;
    __syncthreads();
    for (int t = T_DIM - 1; t >= 0; --t) {
        float p_lo = valid ? base[(size_t)t * C_DIM + lab] : NEGINF;
        float a_cur = isodd ? alb[t * U_DIM + l] : NEGINF;
        float q = (s < 201) ? (p_hi + sh_b[s]) : NEGINF;
        if (s < 201) sh_q[s] = q;
        __syncthreads();
        float q2 = (s + 1 < 201) ? sh_q[s + 1] : NEGINF;
        float q3 = skip2 ? sh_q[s + 2] : NEGINF;
        float cand = lse3f(q, q2, q3);
        float bnew = (t == hl - 1) ? fin0 : cand;
        if (s < 201) sh_b[s] = bnew;
        if (isodd) {
            float bl_t = (a_cur == NEGINF) ? NEGINF : bnew;
            float bp = (t == T_DIM - 1) ? bl_t : log_sub_expf(bl_t, prev_bl + p_hi);
            float x = a_cur + bp - 0.1f * ((float)t / (float)hl);
            if (x != NEGINF) {
                if (x <= m_run) acc += __expf(x - m_run);
                else { acc = acc * __expf(m_run - x) + 1.0f; m_run = x; }
            }
            prev_bl = bl_t;
        }
        __syncthreads();
        p_hi = p_lo;
    }
    if (isodd) sh_lu[l] = (m_run == NEGINF) ? NEGINF : (m_run + __logf(acc));
    __syncthreads();
    if (s == 0) {
        int cnt = 0;
        for (int u = 0; u < U_DIM; ++u) cnt += (sh_lu[u] != NEGINF) ? 1 : 0;
        int last = cnt - 1;
        last = last < 0 ? 0 : (last > U_DIM - 1 ? U_DIM - 1 : last);
        out[b] = -sh_lu[last];
    }
}

extern "C" void kernel_launch(void* const* d_in, const int* in_sizes, int n_in,
                              void* d_out, int out_size, void* d_ws, size_t ws_size,
                              hipStream_t stream) {
    const float* nnet  = (const float*)d_in[0];
    const int*   ys    = (const int*)d_in[1];
    const int*   hlens = (const int*)d_in[2];
    const int*   ylens = (const int*)d_in[3];
    float*       outp  = (float*)d_out;
    const int B = in_sizes[2];
    const size_t TP = T_DIM + 2 * PAD;
    const size_t szP  = (size_t)B * TP * U_DIM;
    const size_t szA  = (size_t)B * AROWS * U_DIM;
    const size_t need = (szP + 2 * szA) * sizeof(float);

    if (ws_size >= need) {
        float* P    = (float*)d_ws;
        float* A    = P + szP;
        float* Braw = A + szA;
        brctc_fused<<<B, 1024, 0, stream>>>(nnet, ys, hlens, ylens, P, A, Braw, outp);
    } else {
        float* A = (float*)d_ws;
        brctc_fwd_fb<<<B, 256, 0, stream>>>(nnet, ys, hlens, ylens, A);
        brctc_bwd_fb<<<B, 256, 0, stream>>>(nnet, ys, hlens, ylens, A, outp);
    }
}

// Round 3
// 416.895 us; speedup vs baseline: 1.2246x; 1.0357x over previous
//
#include <hip/hip_runtime.h>
#include <math.h>

#define T_DIM 1000
#define C_DIM 500
#define U_DIM 100
#define PAD   16          // head/tail padding rows for P
#define AROWS (T_DIM + 5) // A/Braw rows (loss pipeline reads to row T+4)
#define NEGINF (-INFINITY)
#define LROW  128         // LDS row stride in floats; cols 100..127 = -inf pad

typedef float v2f __attribute__((ext_vector_type(2)));

__device__ __forceinline__ v2f splat2(float x) { v2f r; r[0] = x; r[1] = x; return r; }

// ---- packed (2-wide) lse helpers: per-component bit-identical to the scalar
// lse2f/lse3f of rounds 6-11.  All-dead (m==-inf) case produces NaN through
// the exp/log chain; one IEEE v_max(r,-inf) maps NaN->-inf and is identity
// otherwise (v_max_f32 returns the non-NaN operand; not compiler-foldable
// without nnan).  Replaces the old cmp+cndmask pair, bit-identical results.
__device__ __forceinline__ v2f lse2p(v2f X, v2f Y) {
    v2f m, mn;
    m[0]  = fmaxf(X[0], Y[0]); m[1]  = fmaxf(X[1], Y[1]);
    mn[0] = fminf(X[0], Y[0]); mn[1] = fminf(X[1], Y[1]);
    v2f d = mn - m;                       // packed
    v2f e; e[0] = __expf(d[0]); e[1] = __expf(d[1]);
    v2f s = splat2(1.0f) + e;             // packed (1.0f + e, as reference)
    v2f l; l[0] = __logf(s[0]); l[1] = __logf(s[1]);
    v2f r = m + l;                        // packed
    r[0] = fmaxf(r[0], NEGINF);           // NaN (all -inf) -> -inf; else id
    r[1] = fmaxf(r[1], NEGINF);
    return r;
}

__device__ __forceinline__ v2f lse3p(v2f x1, v2f x2, v2f x3) {
    v2f m;
    m[0] = fmaxf(fmaxf(x1[0], x2[0]), x3[0]);
    m[1] = fmaxf(fmaxf(x1[1], x2[1]), x3[1]);
    v2f d1 = x1 - m, d2 = x2 - m, d3 = x3 - m;    // packed
    v2f e1, e2, e3;
    e1[0] = __expf(d1[0]); e1[1] = __expf(d1[1]);
    e2[0] = __expf(d2[0]); e2[1] = __expf(d2[1]);
    e3[0] = __expf(d3[0]); e3[1] = __expf(d3[1]);
    v2f s = (e1 + e2) + e3;               // packed, same assoc as reference
    v2f l; l[0] = __logf(s[0]); l[1] = __logf(s[1]);
    v2f r = m + l;                        // packed
    r[0] = fmaxf(r[0], NEGINF);
    r[1] = fmaxf(r[1], NEGINF);
    return r;
}

// scalar lse3 for the fallback kernels
__device__ __forceinline__ float lse3f(float x1, float x2, float x3) {
    float m = fmaxf(fmaxf(x1, x2), x3);
    if (m == NEGINF) return NEGINF;
    return m + __logf(__expf(x1 - m) + __expf(x2 - m) + __expf(x3 - m));
}

// Bug-compatible replica of reference _log_sub_exp (incl. inf-substitution quirk).
__device__ __forceinline__ float log_sub_expf(float a, float b) {
    bool ia = isinf(a), ib = isinf(b);
    if (!ia && !ib) {
        float ans = b + __logf(__expf(a - b) - 1.0f);
        if (isinf(ans)) ans = -2001.0f + __logf(__expf(1.0f) - 1.0f);
        return ans;
    }
    if (!ia && ib) return a;
    return NEGINF;
}

// DPP lane shifts (validated bit-exact rounds 6-10)
__device__ __forceinline__ float dpp_shr1(float x) {  // lane L <- L-1; lane0 <- -inf
    int r = __builtin_amdgcn_update_dpp(__float_as_int(NEGINF), __float_as_int(x),
                                        0x138, 0xF, 0xF, false);  // wave_shr:1
    return __int_as_float(r);
}
__device__ __forceinline__ float dpp_shl1(float x) {  // lane L <- L+1; lane63 <- -inf
    int r = __builtin_amdgcn_update_dpp(__float_as_int(NEGINF), __float_as_int(x),
                                        0x130, 0xF, 0xF, false);  // wave_shl:1
    return __int_as_float(r);
}

// ---- packed scan step macros (values bit-identical to r10 formulas) --------
// State: A02=(a0,a2), A13=(a1,a3).  P13 comes pre-masked from LDS; blank
// mask mz02 in {0,-inf}; skip masks msk13/mskAB in {0,-inf} (x + 0 == x,
// x + -inf == -inf; -0 impossible by induction).  Stores use a running row
// pointer so offsets fit the 13-bit store immediate.
#define FWD_STEP(off, PL, PBV)                                               \
    {                                                                        \
        v2f P02 = mz02 + splat2(PBV);                                        \
        float am1 = dpp_shr1(A13[1]);                                        \
        v2f Y;  Y[0] = am1;  Y[1] = A13[0];                                  \
        v2f x3 = Y + msk13;                                                  \
        v2f n02 = P02 + lse2p(A02, Y);                                       \
        v2f n13 = (PL) + lse3p(A13, A02, x3);                                \
        A02 = n02; A13 = n13;                                                \
        if (st) pStA[(off)] = make_float2(n13[0], n13[1]);                   \
    }

#define BWD_STEP(tt, off, PL, PBV, FINF)                                     \
    {                                                                        \
        v2f Q02 = (mz02 + splat2(PBV)) + B02;                                \
        v2f Q13 = (PL) + B13;                                                \
        float qd0 = dpp_shl1(Q02[0]);                                        \
        float qd1 = dpp_shl1(Q13[0]);                                        \
        v2f x2; x2[0] = Q02[1]; x2[1] = qd0;                                 \
        v2f x3; x3[0] = Q13[1]; x3[1] = qd1;                                 \
        x3 = x3 + mskAB;                                                     \
        v2f n02 = lse2p(Q02, Q13);                                           \
        v2f n13 = lse3p(Q13, x2, x3);                                        \
        if (FINF) {                                                          \
            bool fin = ((tt) == hl1);                                        \
            B02[0] = fin ? f0 : n02[0]; B02[1] = fin ? f2 : n02[1];          \
            B13[0] = fin ? f1 : n13[0]; B13[1] = fin ? f3 : n13[1];          \
        } else {                                                             \
            B02 = n02; B13 = n13;                                            \
        }                                                                    \
        if (st) pStB[(off)] = make_float2(B13[0], B13[1]);                   \
    }

// LDS float2 read: lane L of row rr (row stride LROW floats, -inf pads)
#define LDF(buf, rr) (((const v2f*)((buf) + (rr) * LROW))[L])

#define FWD_BLOCK(kkv)                                                       \
    {                                                                        \
        v2f r0 = LDF(fb, (kkv) + 0), r1 = LDF(fb, (kkv) + 1);                \
        v2f r2 = LDF(fb, (kkv) + 2), r3 = LDF(fb, (kkv) + 3);                \
        v2f r4 = LDF(fb, (kkv) + 4), r5 = LDF(fb, (kkv) + 5);                \
        v2f r6 = LDF(fb, (kkv) + 6), r7 = LDF(fb, (kkv) + 7);                \
        v2f r8 = LDF(fb, (kkv) + 8), r9 = LDF(fb, (kkv) + 9);                \
        float g0 = fp[(kkv) + 0], g1 = fp[(kkv) + 1], g2 = fp[(kkv) + 2];    \
        float g3 = fp[(kkv) + 3], g4 = fp[(kkv) + 4], g5 = fp[(kkv) + 5];    \
        float g6 = fp[(kkv) + 6], g7 = fp[(kkv) + 7], g8 = fp[(kkv) + 8];    \
        float g9 = fp[(kkv) + 9];                                            \
        FWD_STEP(0 * 50, r0, g0)                                             \
        FWD_STEP(1 * 50, r1, g1)                                             \
        FWD_STEP(2 * 50, r2, g2)                                             \
        FWD_STEP(3 * 50, r3, g3)                                             \
        FWD_STEP(4 * 50, r4, g4)                                             \
        FWD_STEP(5 * 50, r5, g5)                                             \
        FWD_STEP(6 * 50, r6, g6)                                             \
        FWD_STEP(7 * 50, r7, g7)                                             \
        FWD_STEP(8 * 50, r8, g8)                                             \
        FWD_STEP(9 * 50, r9, g9)                                             \
        pStA += 500;                                                         \
    }

#define BWD_BLOCK(kkv, FINF)                                                 \
    {                                                                        \
        v2f r0 = LDF(bbf, (kkv) - 0), r1 = LDF(bbf, (kkv) - 1);              \
        v2f r2 = LDF(bbf, (kkv) - 2), r3 = LDF(bbf, (kkv) - 3);              \
        v2f r4 = LDF(bbf, (kkv) - 4), r5 = LDF(bbf, (kkv) - 5);              \
        v2f r6 = LDF(bbf, (kkv) - 6), r7 = LDF(bbf, (kkv) - 7);              \
        v2f r8 = LDF(bbf, (kkv) - 8), r9 = LDF(bbf, (kkv) - 9);              \
        float g0 = bp[(kkv) - 0], g1 = bp[(kkv) - 1], g2 = bp[(kkv) - 2];    \
        float g3 = bp[(kkv) - 3], g4 = bp[(kkv) - 4], g5 = bp[(kkv) - 5];    \
        float g6 = bp[(kkv) - 6], g7 = bp[(kkv) - 7], g8 = bp[(kkv) - 8];    \
        float g9 = bp[(kkv) - 9];                                            \
        BWD_STEP(tb + (kkv) - 0, -(0 * 50), r0, g0, FINF)                    \
        BWD_STEP(tb + (kkv) - 1, -(1 * 50), r1, g1, FINF)                    \
        BWD_STEP(tb + (kkv) - 2, -(2 * 50), r2, g2, FINF)                    \
        BWD_STEP(tb + (kkv) - 3, -(3 * 50), r3, g3, FINF)                    \
        BWD_STEP(tb + (kkv) - 4, -(4 * 50), r4, g4, FINF)                    \
        BWD_STEP(tb + (kkv) - 5, -(5 * 50), r5, g5, FINF)                    \
        BWD_STEP(tb + (kkv) - 6, -(6 * 50), r6, g6, FINF)                    \
        BWD_STEP(tb + (kkv) - 7, -(7 * 50), r7, g7, FINF)                    \
        BWD_STEP(tb + (kkv) - 8, -(8 * 50), r8, g8, FINF)                    \
        BWD_STEP(tb + (kkv) - 9, -(9 * 50), r9, g9, FINF)                    \
        pStB -= 500;                                                         \
    }

// ---- loss step (verbatim r10) ----------------------------------------------
#define LSTEP(tt, RA, RB, RP)                                                \
    {                                                                        \
        float a_nx = (RA), br_nx = (RB), p_nx = (RP);                        \
        float bl   = (a_t  == NEGINF) ? NEGINF : braw_t;                     \
        float term = (a_nx == NEGINF) ? NEGINF : (br_nx + p_nx);             \
        float bp = log_sub_expf(bl, term);                                   \
        float x = a_t + bp - 0.1f * (float)(tt) * inv_hl;                    \
        if (x != NEGINF) {                                                   \
            float nm = fmaxf(m, x);                                          \
            ssum = ssum * __expf(m - nm) + __expf(x - nm);                   \
            m = nm;                                                          \
        }                                                                    \
        a_t = a_nx; braw_t = br_nx;                                          \
    }

// ---- loader gather: 50 rows x (100 labels + blank) straight from nnet ------
// LDS copy is pre-masked: labels with u >= yl -> NEGINF (same as the old
// per-step v1/v3 cndmask); global P keeps raw values (loss masks itself).
__device__ __forceinline__ void gather_chunk(
    const float* __restrict__ nb, const int* __restrict__ shY, int yl,
    float* __restrict__ lds, float* __restrict__ ldsb,
    float* __restrict__ Pg /* global row0 base, or nullptr */,
    int row0, int j)
{
#pragma unroll
    for (int k = 0; k < 15; ++k) {
        int i = j + k * 448;                 // 448 loader threads per direction
        if (i < 6400) {                      // 50 rows x 128 slots
            int r = i >> 7, q = i & 127;
            if (q <= 100) {
                int row = row0 + r;
                int col = (q < 100) ? shY[q] : 0;
                float v = (row < T_DIM) ? nb[(size_t)row * C_DIM + col] : NEGINF;
                if (q < 100) {
                    lds[r * LROW + q] = (q < yl) ? v : NEGINF;
                    if (Pg) Pg[(size_t)r * U_DIM + q] = v;
                } else {
                    ldsb[r] = v;
                }
            }
        }
    }
}

// ---- fused: LDS double-buffered chunks; loader waves gather from nnet ------
extern "C" __global__ void __launch_bounds__(1024)
brctc_fused(const float* __restrict__ nnet, const int* __restrict__ ys,
            const int* __restrict__ hlens, const int* __restrict__ ylens,
            float* __restrict__ P,
            float* __restrict__ A, float* __restrict__ Braw,
            float* __restrict__ out)
{
    const int b = blockIdx.x;
    const int tid = threadIdx.x;
    const int w = tid >> 6, L = tid & 63;
    const int hl = hlens[b], yl = ylens[b];
    const int hl1 = hl - 1;
    const size_t TP = T_DIM + 2 * PAD;
    const float* nb = nnet + (size_t)b * T_DIM * C_DIM;
    float* Pw = P + ((size_t)b * TP + PAD) * U_DIM;   // rows 0..T (+tail pad)
    const float* Pb = Pw;                             // loss-phase reads
    const int* ysb = ys + b * U_DIM;
    float* Ab = A    + (size_t)b * AROWS * U_DIM;
    float* Bb = Braw + (size_t)b * AROWS * U_DIM;

    // LDS: 2 dirs x 2 buffers x 50 rows x LROW floats (cols>=100 are -inf pad)
    __shared__ __align__(16) float fbuf[2][50 * LROW];
    __shared__ __align__(16) float bbuf[2][50 * LROW];
    __shared__ float fpb[2][56], bpb[2][56];
    __shared__ float shm[8][U_DIM], shs[8][U_DIM], shlu[U_DIM];
    __shared__ int shY[U_DIM];

    if (tid < U_DIM) shY[tid] = ysb[tid];

    // ---- per-lane scan constants (computed by all threads, used by waves 0/1)
    const int s0_ = 4 * L, s1 = 4 * L + 1, s2_ = 4 * L + 2, s3 = 4 * L + 3;
    const int u1 = 2 * L;
    const int lab1 = ysb[min(u1, U_DIM - 1)];
    const int lab3 = ysb[min(u1 + 1, U_DIM - 1)];
    const int labm = ysb[min(max(u1 - 1, 0), U_DIM - 1)];
    const int labn = ysb[min(u1 + 2, U_DIM - 1)];
    const bool skip1 = (s1 >= 3) && (lab1 != labm);
    const bool skip3 = (lab3 != lab1);
    const bool skipA = (s1 < 199) && (lab3 != lab1);
    const bool skipB = (s3 < 199) && (labn != lab3);
    const int ty = 2 * yl;
    const bool v0 = (s0_ <= 200) && (s0_ <= ty);
    const bool v2_ = (s2_ <= 200) && (s2_ <= ty);
    const bool st = (L < 50);
    v2f mz02;  mz02[0]  = v0    ? 0.0f : NEGINF; mz02[1]  = v2_   ? 0.0f : NEGINF;
    v2f msk13; msk13[0] = skip1 ? 0.0f : NEGINF; msk13[1] = skip3 ? 0.0f : NEGINF;
    v2f mskAB; mskAB[0] = skipA ? 0.0f : NEGINF; mskAB[1] = skipB ? 0.0f : NEGINF;
    const float f0 = (s0_ == ty || s0_ == ty - 1) ? 0.0f : NEGINF;
    const float f1 = (s1  == ty || s1  == ty - 1) ? 0.0f : NEGINF;
    const float f2 = (s2_ == ty || s2_ == ty - 1) ? 0.0f : NEGINF;
    const float f3 = (s3  == ty || s3  == ty - 1) ? 0.0f : NEGINF;

    v2f A02, A13, B02, B13;
    A02[0] = (L == 0) ? 0.0f : NEGINF; A02[1] = NEGINF;
    A13[0] = NEGINF; A13[1] = NEGINF;
    B02[0] = NEGINF; B02[1] = NEGINF;
    B13[0] = NEGINF; B13[1] = NEGINF;

    __syncthreads();   // shY ready for loaders

    // ---- prologue: -inf pads (once) + gather fwd chunk 0, bwd chunk 19 ----
    if (w >= 2) {
        int j2 = tid - 128;                 // 0..895
        for (int i = j2; i < 4 * 50 * 28; i += 896) {
            int buf = i / (50 * 28), rem = i % (50 * 28);
            int r = rem / 28, q = 100 + rem % 28;
            float* base = (buf == 0) ? fbuf[0] : (buf == 1) ? fbuf[1]
                        : (buf == 2) ? bbuf[0] : bbuf[1];
            base[r * LROW + q] = NEGINF;
        }
    }
    if (w >= 2 && w < 9) {                 // fwd loaders (waves 2..8, 448 thr)
        int j = tid - 128;
        gather_chunk(nb, shY, yl, fbuf[0], fpb[0], Pw, 0, j);
        if (j < U_DIM) Pw[(size_t)T_DIM * U_DIM + j] = NEGINF;  // global P row 1000
    } else if (w >= 9) {                   // bwd loaders (waves 9..15)
        int j = tid - 576;
        gather_chunk(nb, shY, yl, bbuf[0], bpb[0], nullptr, 951, j);
    }
    __syncthreads();

    // ---- 20 chunks of 50 steps --------------------------------------------
    for (int c = 0; c < 20; ++c) {
        if (w == 0) {                       // forward scan, chunk c
            const float* fb = fbuf[c & 1];
            const float* fp = fpb[c & 1];
            const int tb = 50 * c;
            float2* pStA = (float2*)(Ab + (size_t)tb * U_DIM) + L;
            for (int kk = 0; kk < 50; kk += 10) FWD_BLOCK(kk)
        } else if (w == 1) {                // backward scan, chunk 19-c
            const float* bbf = bbuf[c & 1];
            const float* bp  = bpb[c & 1];
            const int cc = 19 - c;
            const int tb = 50 * cc;         // steps tb+49 .. tb; slot = t - tb
            float2* pStB = (float2*)(Bb + (size_t)(tb + 49) * U_DIM) + L;
            if (hl1 >= tb && hl1 <= tb + 49) {
                for (int kk = 49; kk >= 9; kk -= 10) BWD_BLOCK(kk, true)
            } else {
                for (int kk = 49; kk >= 9; kk -= 10) BWD_BLOCK(kk, false)
            }
        } else if (c < 19) {                // loaders: gather next buffers from nnet
            if (w < 9) {
                int j = tid - 128;
                int row0 = (c + 1) * 50;                       // rows 50..950
                gather_chunk(nb, shY, yl, fbuf[(c + 1) & 1], fpb[(c + 1) & 1],
                             Pw + (size_t)row0 * U_DIM, row0, j);
            } else {
                int j = tid - 576;
                int row0 = (18 - c) * 50 + 1;                  // rows 1..901
                gather_chunk(nb, shY, yl, bbuf[(c + 1) & 1], bpb[(c + 1) & 1],
                             nullptr, row0, j);
            }
        }
        __syncthreads();
    }

    // ---- post-fill: alpha rows >= hl and sentinel row T are NEGINF --------
    {
        const int r0f = min(hl, T_DIM);
        const int nrow = T_DIM + 1 - r0f;
        const int tot = nrow * 50;
        for (int i = tid; i < tot; i += 1024) {
            const int rr = r0f + i / 50, cc2 = i % 50;
            ((float2*)(Ab + (size_t)rr * U_DIM))[cc2] = make_float2(NEGINF, NEGINF);
        }
    }
    __syncthreads();

    // ---- loss phase (verbatim r10 structure) ------------------------------
    {
        const int u = tid & 127;
        const int c = tid >> 7;               // 0..7
        if (u < U_DIM) {
            const bool valu = (u < yl);
            const float inv_hl = 1.0f / (float)hl;
            const int t0 = 125 * c;
            float a_t    = Ab[(size_t)t0 * U_DIM + u];
            float braw_t = Bb[(size_t)t0 * U_DIM + u];
            float aA0 = Ab[(long)(t0 + 1) * U_DIM + u];
            float aA1 = Ab[(long)(t0 + 2) * U_DIM + u];
            float aA2 = Ab[(long)(t0 + 3) * U_DIM + u];
            float aA3 = Ab[(long)(t0 + 4) * U_DIM + u];
            float bA0 = Bb[(long)(t0 + 1) * U_DIM + u];
            float bA1 = Bb[(long)(t0 + 2) * U_DIM + u];
            float bA2 = Bb[(long)(t0 + 3) * U_DIM + u];
            float bA3 = Bb[(long)(t0 + 4) * U_DIM + u];
            float pA0 = valu ? Pb[(long)(t0 + 1) * U_DIM + u] : NEGINF;
            float pA1 = valu ? Pb[(long)(t0 + 2) * U_DIM + u] : NEGINF;
            float pA2 = valu ? Pb[(long)(t0 + 3) * U_DIM + u] : NEGINF;
            float pA3 = valu ? Pb[(long)(t0 + 4) * U_DIM + u] : NEGINF;
            float m = NEGINF, ssum = 0.0f;
            for (int kb = 0; kb <= 120; kb += 4) {
                long nr = (long)(t0 + kb + 5);
                float aB0 = Ab[(nr + 0) * U_DIM + u];
                float aB1 = Ab[(nr + 1) * U_DIM + u];
                float aB2 = Ab[(nr + 2) * U_DIM + u];
                float aB3 = Ab[(nr + 3) * U_DIM + u];
                float bB0 = Bb[(nr + 0) * U_DIM + u];
                float bB1 = Bb[(nr + 1) * U_DIM + u];
                float bB2 = Bb[(nr + 2) * U_DIM + u];
                float bB3 = Bb[(nr + 3) * U_DIM + u];
                float pB0 = valu ? Pb[(nr + 0) * U_DIM + u] : NEGINF;
                float pB1 = valu ? Pb[(nr + 1) * U_DIM + u] : NEGINF;
                float pB2 = valu ? Pb[(nr + 2) * U_DIM + u] : NEGINF;
                float pB3 = valu ? Pb[(nr + 3) * U_DIM + u] : NEGINF;
                LSTEP(t0 + kb + 0, aA0, bA0, pA0)
                LSTEP(t0 + kb + 1, aA1, bA1, pA1)
                LSTEP(t0 + kb + 2, aA2, bA2, pA2)
                LSTEP(t0 + kb + 3, aA3, bA3, pA3)
                aA0 = aB0; aA1 = aB1; aA2 = aB2; aA3 = aB3;
                bA0 = bB0; bA1 = bB1; bA2 = bB2; bA3 = bB3;
                pA0 = pB0; pA1 = pB1; pA2 = pB2; pA3 = pB3;
            }
            LSTEP(t0 + 124, aA0, bA0, pA0)
            shm[c][u] = m; shs[c][u] = ssum;
        }
    }
    __syncthreads();
    if (tid < U_DIM) {
        float M = NEGINF;
#pragma unroll
        for (int c = 0; c < 8; ++c) M = fmaxf(M, shm[c][tid]);
        float lu = NEGINF;
        if (M != NEGINF) {
            float s = 0.0f;
#pragma unroll
            for (int c = 0; c < 8; ++c) {
                float mc = shm[c][tid];
                if (mc != NEGINF) s += shs[c][tid] * __expf(mc - M);
            }
            lu = M + __logf(s);
        }
        shlu[tid] = lu;
    }
    __syncthreads();
    if (tid == 0) {
        int cnt = 0;
        for (int u = 0; u < U_DIM; ++u) cnt += (shlu[u] != NEGINF) ? 1 : 0;
        int last = cnt - 1;
        last = last < 0 ? 0 : (last > U_DIM - 1 ? U_DIM - 1 : last);
        out[b] = -shlu[last];
    }
}

// =================== fallback (small ws): round-1-style direct path =========
extern "C" __global__ void __launch_bounds__(256)
brctc_fwd_fb(const float* __restrict__ nnet, const int* __restrict__ ys,
             const int* __restrict__ hlens, const int* __restrict__ ylens,
             float* __restrict__ a_l)
{
    const int b = blockIdx.x;
    const int s = threadIdx.x;
    __shared__ float sh_a[201];
    __shared__ int   sh_ys[U_DIM];
    if (s < U_DIM) sh_ys[s] = ys[b * U_DIM + s];
    __syncthreads();
    const int hl = hlens[b], yl = ylens[b];
    int lab = 0; bool skip = false;
    if (s < 201) {
        if (s & 1) lab = sh_ys[(s - 1) >> 1];
        if ((s & 1) && s >= 3) skip = (sh_ys[(s - 1) >> 1] != sh_ys[(s - 3) >> 1]);
        sh_a[s] = (s == 0) ? 0.0f : NEGINF;
    }
    const bool valid = (s < 201) && (s <= 2 * yl);
    const bool isodd = (s < 201) && (s & 1);
    const int l = (s - 1) >> 1;
    const float* base = nnet + (size_t)b * T_DIM * C_DIM;
    float* alb = a_l + (size_t)b * T_DIM * U_DIM;
    __syncthreads();
    float p_cur = valid ? base[lab] : NEGINF;
    for (int t = 0; t < T_DIM; ++t) {
        float p_nxt = (valid && (t + 1 < T_DIM)) ? base[(size_t)(t + 1) * C_DIM + lab] : NEGINF;
        float x1 = (s < 201) ? sh_a[s] : NEGINF;
        float x2 = (s >= 1 && s < 201) ? sh_a[s - 1] : NEGINF;
        float x3 = skip ? sh_a[s - 2] : NEGINF;
        float anew = p_cur + lse3f(x1, x2, x3);
        __syncthreads();
        if (s < 201) sh_a[s] = anew;
        if (isodd) alb[t * U_DIM + l] = (t < hl) ? anew : NEGINF;
        __syncthreads();
        p_cur = p_nxt;
    }
}

extern "C" __global__ void __launch_bounds__(256)
brctc_bwd_fb(const float* __restrict__ nnet, const int* __restrict__ ys,
             const int* __restrict__ hlens, const int* __restrict__ ylens,
             const float* __restrict__ a_l, float* __restrict__ out)
{
    const int b = blockIdx.x;
    const int s = threadIdx.x;
    __shared__ float sh_b[201], sh_q[201], sh_lu[U_DIM];
    __shared__ int sh_ys[U_DIM];
    if (s < U_DIM) sh_ys[s] = ys[b * U_DIM + s];
    __syncthreads();
    const int hl = hlens[b], yl = ylens[b];
    int lab = 0; bool skip2 = false;
    if (s < 201) {
        if (s & 1) lab = sh_ys[(s - 1) >> 1];
        int s2 = s + 2;
        if (s2 < 201 && (s2 & 1) && s2 >= 3)
            skip2 = (sh_ys[(s2 - 1) >> 1] != sh_ys[(s2 - 3) >> 1]);
        sh_b[s] = NEGINF;
    }
    const bool valid = (s < 201) && (s <= 2 * yl);
    const bool isodd = (s < 201) && (s & 1);
    const int l = (s - 1) >> 1;
    const float fin0 = (s == 2 * yl || s == 2 * yl - 1) ? 0.0f : NEGINF;
    const float* base = nnet + (size_t)b * T_DIM * C_DIM;
    const float* alb = a_l + (size_t)b * T_DIM * U_DIM;
    float m_run = NEGINF, acc = 0.0f, prev_bl = NEGINF, p_hi = NEGINF;
    __syncthreads();
    for (int t = T_DIM - 1; t >= 0; --t) {
        float p_lo = valid ? base[(size_t)t * C_DIM + lab] : NEGINF;
        float a_cur = isodd ? alb[t * U_DIM + l] : NEGINF;
        float q = (s < 201) ? (p_hi + sh_b[s]) : NEGINF;
        if (s < 201) sh_q[s] = q;
        __syncthreads();
        float q2 = (s + 1 < 201) ? sh_q[s + 1] : NEGINF;
        float q3 = skip2 ? sh_q[s + 2] : NEGINF;
        float cand = lse3f(q, q2, q3);
        float bnew = (t == hl - 1) ? fin0 : cand;
        if (s < 201) sh_b[s] = bnew;
        if (isodd) {
            float bl_t = (a_cur == NEGINF) ? NEGINF : bnew;
            float bp = (t == T_DIM - 1) ? bl_t : log_sub_expf(bl_t, prev_bl + p_hi);
            float x = a_cur + bp - 0.1f * ((float)t / (float)hl);
            if (x != NEGINF) {
                if (x <= m_run) acc += __expf(x - m_run);
                else { acc = acc * __expf(m_run - x) + 1.0f; m_run = x; }
            }
            prev_bl = bl_t;
        }
        __syncthreads();
        p_hi = p_lo;
    }
    if (isodd) sh_lu[l] = (m_run == NEGINF) ? NEGINF : (m_run + __logf(acc));
    __syncthreads();
    if (s == 0) {
        int cnt = 0;
        for (int u = 0; u < U_DIM; ++u) cnt += (sh_lu[u] != NEGINF) ? 1 : 0;
        int last = cnt - 1;
        last = last < 0 ? 0 : (last > U_DIM - 1 ? U_DIM - 1 : last);
        out[b] = -sh_lu[last];
    }
}

extern "C" void kernel_launch(void* const* d_in, const int* in_sizes, int n_in,
                              void* d_out, int out_size, void* d_ws, size_t ws_size,
                              hipStream_t stream) {
    const float* nnet  = (const float*)d_in[0];
    const int*   ys    = (const int*)d_in[1];
    const int*   hlens = (const int*)d_in[2];
    const int*   ylens = (const int*)d_in[3];
    float*       outp  = (float*)d_out;
    const int B = in_sizes[2];
    const size_t TP = T_DIM + 2 * PAD;
    const size_t szP  = (size_t)B * TP * U_DIM;
    const size_t szA  = (size_t)B * AROWS * U_DIM;
    const size_t need = (szP + 2 * szA) * sizeof(float);

    if (ws_size >= need) {
        float* P    = (float*)d_ws;
        float* A    = P + szP;
        float* Braw = A + szA;
        brctc_fused<<<B, 1024, 0, stream>>>(nnet, ys, hlens, ylens, P, A, Braw, outp);
    } else {
        float* A = (float*)d_ws;
        brctc_fwd_fb<<<B, 256, 0, stream>>>(nnet, ys, hlens, ylens, A);
        brctc_bwd_fb<<<B, 256, 0, stream>>>(nnet, ys, hlens, ylens, A, outp);
    }
}